// Round 1
// 15815.063 us; speedup vs baseline: 1.3667x; 1.3667x over previous
//
#include <hip/hip_runtime.h>
#include <math.h>

#define Vv    32000
#define Dd    1024
#define Hh    16
#define HKVn  4
#define FFn   4096
#define Ln    8
#define HDn   64
#define Bn    2
#define Sn    1024
#define NT    (Bn*Sn)        // 2048 token rows
#define KVD   (HKVn*HDn)     // 256
#define EPSf  1e-6f

typedef _Float16 half8 __attribute__((ext_vector_type(8)));
typedef float    f32x4 __attribute__((ext_vector_type(4)));

// ---------------- embedding gather: x[n,:] = embed[tok[n],:]  (float4 vectorized)
__global__ __launch_bounds__(256) void embed_kernel(const int* __restrict__ tok,
                                                    const float* __restrict__ embed,
                                                    float* __restrict__ x) {
    int n = blockIdx.x;
    int t = tok[n];
    const float4* src = (const float4*)(embed + (size_t)t * Dd);
    float4* dst = (float4*)(x + (size_t)n * Dd);
    dst[threadIdx.x] = src[threadIdx.x];   // 256 threads * 4 floats = 1024 = Dd
}

// ---------------- RMSNorm: out[n,:] = x[n,:] * rsqrt(mean(x^2)+eps) * w
__global__ __launch_bounds__(256) void rmsnorm_kernel(const float* __restrict__ x,
                                                      const float* __restrict__ w,
                                                      float* __restrict__ out) {
    int n = blockIdx.x;
    const float* xr = x + (size_t)n * Dd;
    float* orow = out + (size_t)n * Dd;
    float ss = 0.f;
    for (int d = threadIdx.x; d < Dd; d += 256) { float v = xr[d]; ss += v * v; }
    for (int off = 32; off; off >>= 1) ss += __shfl_xor(ss, off);
    __shared__ float red[4];
    __shared__ float rinv;
    int wid = threadIdx.x >> 6;
    if ((threadIdx.x & 63) == 0) red[wid] = ss;
    __syncthreads();
    if (threadIdx.x == 0) {
        float tot = red[0] + red[1] + red[2] + red[3];
        rinv = rsqrtf(tot / (float)Dd + EPSf);
    }
    __syncthreads();
    float r = rinv;
    for (int d = threadIdx.x; d < Dd; d += 256)
        orow[d] = xr[d] * r * w[d];
}

// ---------------- fp16-MFMA tiled GEMM, fp32 in/out, fp32 accumulate.
// C[M,N] = (addsrc?addsrc:0) + A[M,K] @ W   where W is [K,N] (BT=false) or [N,K] (BT=true).
// Tile 128x128, BK=32, 256 threads = 4 waves in 2x2, each wave 64x64 via 4x4 MFMA 16x16x32 frags.
// LDS layout fragment-major: [kc][row][8] halfs -> ds_read_b128 contiguous per 16-lane group.
#define TM 128
#define TN 128
#define TK 32

template<bool BT>
__global__ __launch_bounds__(256) void gemm_f16(const float* __restrict__ A,
                                                const float* __restrict__ W,
                                                const float* __restrict__ addsrc,
                                                float* __restrict__ C,
                                                int M, int N, int K) {
    __shared__ __align__(16) _Float16 As[4][TM][8];
    __shared__ __align__(16) _Float16 Bs[4][TN][8];
    int tid  = threadIdx.x;
    int lane = tid & 63, wid = tid >> 6;
    int wm = (wid >> 1) * 64, wn = (wid & 1) * 64;
    int m0 = blockIdx.y * TM, n0 = blockIdx.x * TN;
    f32x4 acc[4][4] = {};

    // staging assignments
    int am  = tid & 127;            // A: row within tile
    int akc = (tid >> 7) * 2;       // A: first k-chunk (of 8 k) this thread stages
    int bn  = tid & 127;            // B: col within tile
    int bk0 = (tid >> 7) * 16;      // B: first k-row this thread stages (16 rows)

    // fragment read indices
    int fr  = lane & 15;            // row (A) / col (B) within 16
    int kcf = lane >> 4;            // k-chunk 0..3 (k = kcf*8 + 0..7)

    const float* Arow = A + (size_t)(m0 + am) * K;

    for (int k0 = 0; k0 < K; k0 += TK) {
        // ---- stage A (128x32 fp32 -> fp16), 16 elems/thread
#pragma unroll
        for (int c = 0; c < 2; ++c) {
            int kc = akc + c;
            const float* ap = Arow + k0 + kc * 8;
            half8 ha;
#pragma unroll
            for (int j = 0; j < 8; ++j) ha[j] = (_Float16)ap[j];
            *(half8*)(&As[kc][am][0]) = ha;
        }
        // ---- stage B (32x128 fp32 -> fp16), 16 elems/thread
        float tmpb[16];
        if (!BT) {
            const float* wp = W + (size_t)(k0 + bk0) * N + n0 + bn;
#pragma unroll
            for (int j = 0; j < 16; ++j) tmpb[j] = wp[(size_t)j * N];
        } else {
            const float* wp = W + (size_t)(n0 + bn) * K + k0 + bk0;
#pragma unroll
            for (int j = 0; j < 16; ++j) tmpb[j] = wp[j];
        }
#pragma unroll
        for (int c = 0; c < 2; ++c) {
            half8 hb;
#pragma unroll
            for (int j = 0; j < 8; ++j) hb[j] = (_Float16)tmpb[c * 8 + j];
            *(half8*)(&Bs[(bk0 >> 3) + c][bn][0]) = hb;
        }
        __syncthreads();
        // ---- fragments + MFMA
        half8 af[4], bf[4];
#pragma unroll
        for (int i = 0; i < 4; ++i) af[i] = *(const half8*)(&As[kcf][wm + i * 16 + fr][0]);
#pragma unroll
        for (int j = 0; j < 4; ++j) bf[j] = *(const half8*)(&Bs[kcf][wn + j * 16 + fr][0]);
#pragma unroll
        for (int i = 0; i < 4; ++i)
#pragma unroll
            for (int j = 0; j < 4; ++j)
                acc[i][j] = __builtin_amdgcn_mfma_f32_16x16x32_f16(af[i], bf[j], acc[i][j], 0, 0, 0);
        __syncthreads();
    }
    // ---- epilogue: C/D layout col=lane&15, row=(lane>>4)*4+reg
    int r0 = (lane >> 4) * 4;
#pragma unroll
    for (int i = 0; i < 4; ++i)
#pragma unroll
        for (int r = 0; r < 4; ++r) {
            size_t rowg = (size_t)(m0 + wm + i * 16 + r0 + r);
#pragma unroll
            for (int j = 0; j < 4; ++j) {
                size_t idx = rowg * N + (n0 + wn + j * 16 + fr);
                C[idx] = (addsrc ? addsrc[idx] : 0.f) + acc[i][j][r];
            }
        }
}

// ---------------- RoPE in-place on q [NT, H*HD] and k [NT, HKV*HD]
__global__ void rope_kernel(float* __restrict__ q, float* __restrict__ k) {
    int n = blockIdx.x;
    int s = n & (Sn - 1);
    int tid = threadIdx.x;   // 640 threads: 512 q pairs + 128 k pairs
    float* base;
    int j;
    if (tid < 512) { int head = tid >> 5; j = tid & 31; base = q + (size_t)n * (Hh * HDn) + head * HDn + j; }
    else { int t2 = tid - 512; int head = t2 >> 5; j = t2 & 31; base = k + (size_t)n * KVD + head * HDn + j; }
    float inv = powf(10000.f, -(float)j / 32.f);
    float ang = (float)s * inv;
    float c = cosf(ang), sn = sinf(ang);
    float x1 = base[0], x2 = base[32];
    base[0]  = x1 * c - x2 * sn;
    base[32] = x2 * c + x1 * sn;
}

// ---------------- causal GQA attention, one wave per (b,h,s) query row
__global__ __launch_bounds__(64) void attn_kernel(const float* __restrict__ q,
                                                  const float* __restrict__ k,
                                                  const float* __restrict__ v,
                                                  float* __restrict__ o) {
    int s = blockIdx.x, h = blockIdx.y, b = blockIdx.z;
    int lane = threadIdx.x;
    int g = h >> 2;   // NREP = 4
    float qv = q[((size_t)(b * Sn + s)) * (Hh * HDn) + h * HDn + lane];
    float m = -INFINITY, l = 0.f, acc = 0.f;
    const float scale = 0.125f;   // 1/sqrt(64)
    const float* kb = k + (size_t)b * Sn * KVD + g * HDn + lane;
    const float* vb = v + (size_t)b * Sn * KVD + g * HDn + lane;
    for (int t = 0; t <= s; ++t) {
        float p = qv * kb[(size_t)t * KVD];
        for (int off = 32; off; off >>= 1) p += __shfl_xor(p, off);
        p *= scale;
        float mnew = fmaxf(m, p);
        float corr = __expf(m - mnew);
        float w = __expf(p - mnew);
        l = l * corr + w;
        acc = acc * corr + w * vb[(size_t)t * KVD];
        m = mnew;
    }
    o[((size_t)(b * Sn + s)) * (Hh * HDn) + h * HDn + lane] = acc / l;
}

// ---------------- silu(g) * u -> g
__global__ void silu_mul_kernel(float* __restrict__ g, const float* __restrict__ u, int n) {
    int i = blockIdx.x * blockDim.x + threadIdx.x;
    if (i < n) {
        float x = g[i];
        float sig = 1.f / (1.f + expf(-x));
        g[i] = x * sig * u[i];
    }
}

extern "C" void kernel_launch(void* const* d_in, const int* in_sizes, int n_in,
                              void* d_out, int out_size, void* d_ws, size_t ws_size,
                              hipStream_t stream) {
    const int*   tokens  = (const int*)d_in[0];
    const float* embed   = (const float*)d_in[1];
    const float* wq      = (const float*)d_in[2];
    const float* wk      = (const float*)d_in[3];
    const float* wv      = (const float*)d_in[4];
    const float* wo      = (const float*)d_in[5];
    const float* w_gate  = (const float*)d_in[6];
    const float* w_up    = (const float*)d_in[7];
    const float* w_down  = (const float*)d_in[8];
    const float* norm1_w = (const float*)d_in[9];
    const float* norm2_w = (const float*)d_in[10];
    const float* final_w = (const float*)d_in[11];
    float* logits = (float*)d_out;

    float* ws = (float*)d_ws;
    float* x   = ws;                       // NT*Dd
    float* h   = x   + (size_t)NT * Dd;    // NT*Dd
    float* q   = h   + (size_t)NT * Dd;    // NT*Dd
    float* kb  = q   + (size_t)NT * Dd;    // NT*KVD
    float* vb  = kb  + (size_t)NT * KVD;   // NT*KVD
    float* ao  = vb  + (size_t)NT * KVD;   // NT*Dd
    float* gg  = ao  + (size_t)NT * Dd;    // NT*FFn
    float* uu  = gg  + (size_t)NT * FFn;   // NT*FFn

    embed_kernel<<<NT, 256, 0, stream>>>(tokens, embed, x);

    for (int l = 0; l < Ln; ++l) {
        const float* wq_l = wq + (size_t)l * Dd * (Hh * HDn);
        const float* wk_l = wk + (size_t)l * Dd * KVD;
        const float* wv_l = wv + (size_t)l * Dd * KVD;
        const float* wo_l = wo + (size_t)l * (Hh * HDn) * Dd;
        const float* wg_l = w_gate + (size_t)l * Dd * FFn;
        const float* wu_l = w_up   + (size_t)l * Dd * FFn;
        const float* wd_l = w_down + (size_t)l * FFn * Dd;

        rmsnorm_kernel<<<NT, 256, 0, stream>>>(x, norm1_w + (size_t)l * Dd, h);

        gemm_f16<false><<<dim3(Dd / TN, NT / TM), 256, 0, stream>>>(h, wq_l, nullptr, q,  NT, Dd,  Dd);
        gemm_f16<false><<<dim3(KVD / TN, NT / TM), 256, 0, stream>>>(h, wk_l, nullptr, kb, NT, KVD, Dd);
        gemm_f16<false><<<dim3(KVD / TN, NT / TM), 256, 0, stream>>>(h, wv_l, nullptr, vb, NT, KVD, Dd);

        rope_kernel<<<NT, 640, 0, stream>>>(q, kb);

        attn_kernel<<<dim3(Sn, Hh, Bn), 64, 0, stream>>>(q, kb, vb, ao);

        gemm_f16<false><<<dim3(Dd / TN, NT / TM), 256, 0, stream>>>(ao, wo_l, x, x, NT, Dd, Dd);

        rmsnorm_kernel<<<NT, 256, 0, stream>>>(x, norm2_w + (size_t)l * Dd, h);

        gemm_f16<false><<<dim3(FFn / TN, NT / TM), 256, 0, stream>>>(h, wg_l, nullptr, gg, NT, FFn, Dd);
        gemm_f16<false><<<dim3(FFn / TN, NT / TM), 256, 0, stream>>>(h, wu_l, nullptr, uu, NT, FFn, Dd);

        int nsil = NT * FFn;
        silu_mul_kernel<<<(nsil + 255) / 256, 256, 0, stream>>>(gg, uu, nsil);

        gemm_f16<false><<<dim3(Dd / TN, NT / TM), 256, 0, stream>>>(gg, wd_l, x, x, NT, Dd, FFn);
    }

    rmsnorm_kernel<<<NT, 256, 0, stream>>>(x, final_w, h);
    gemm_f16<true><<<dim3(Vv / TN, NT / TM), 256, 0, stream>>>(h, embed, nullptr, logits, NT, Vv, Dd);
}